// Round 21
// baseline (289.593 us; speedup 1.0000x reference)
//
#include <hip/hip_runtime.h>
#include <math.h>

#define NSH 1195
#define NU  805
#define NI  390
#define DD  64
#define BROWS 65536
#define ESH 100000
#define KPAD 416    // esWT row stride (global)
#define SPAD 392    // s_P row stride
#define NUPAD 832
#define KA  1216    // dense-A row stride & padded node count (38*32)

typedef _Float16 f16;
typedef _Float16 f16x2 __attribute__((ext_vector_type(2)));
typedef _Float16 f16x8 __attribute__((ext_vector_type(8)));
typedef float f32x4 __attribute__((ext_vector_type(4)));

// ---------------- ws layout (float units) ----------------
#define OFF_STATS  0u         // 128
#define OFF_ESWT   128u       // 64*416 f16
#define OFF_EH     13440u     // 832*64 f16
#define OFF_SHEMBT 40064u     // 64*1216 f16
#define OFF_H1T    78976u     // 64*1216 f16
#define OFF_EPRE   117888u    // e_pre 4194304 f32; A (1216*1216 f32) aliases its head

// ---------------- prep: zero A + build shembT + zero stats/esWT-pad/eh16-pad ----------------
__global__ __launch_bounds__(256) void prep_kernel(const float* __restrict__ shemb,
                                                   float* __restrict__ A,
                                                   f16* __restrict__ shembT,
                                                   float* __restrict__ stats,
                                                   f16* __restrict__ esWT,
                                                   f16* __restrict__ eh16) {
    int b = blockIdx.x, tid = threadIdx.x;
    if (b < 1444) {
        int i = b * 256 + tid;
        *(f32x4*)&A[i * 4] = (f32x4){0.f, 0.f, 0.f, 0.f};
    } else if (b < 1748) {
        int i = (b - 1444) * 256 + tid;
        int d = i / KA, k = i - d * KA;
        shembT[i] = (k < NSH) ? (f16)shemb[k * DD + d] : (f16)0.f;
    } else {
        for (int i = tid; i < 128; i += 256) stats[i] = 0.f;
        for (int i = tid; i < 832; i += 256) {
            int d = i / 13, j = i - d * 13;
            *(uint32_t*)&esWT[d * KPAD + 390 + j * 2] = 0u;
        }
        for (int i = tid; i < 864; i += 256)
            ((uint32_t*)eh16)[NU * 32 + i] = 0u;
    }
}

// ---------------- build dense A: A[dst][src] += 1 ----------------
__global__ __launch_bounds__(256) void build_A(const int* __restrict__ edges,
                                               float* __restrict__ A) {
    int e = blockIdx.x * 256 + threadIdx.x;
    if (e < ESH)
        atomicAdd(&A[edges[ESH + e] * KA + edges[e]], 1.0f);
}

// ---------------- gcn1: [R14-verified math] 38 blocks x 128 thr ----------------
__global__ __launch_bounds__(128) void gcn1_mfma(const float* __restrict__ A,
                                                 const f16* __restrict__ shembT,
                                                 const float* __restrict__ W1,
                                                 const float* __restrict__ b1,
                                                 f16* __restrict__ h1T) {
    __shared__ __align__(16) f16 s_w1[DD * 72];
    __shared__ __align__(16) f16 s_agg[2][16 * 72];
    int tid = threadIdx.x;
    for (int i = tid; i < DD * DD; i += 128)
        s_w1[(i >> 6) * 72 + (i & 63)] = (f16)W1[i];
    __syncthreads();

    int lane = tid & 63, w = tid >> 6;
    int l15 = lane & 15, lk = lane >> 4;
    int mbase = blockIdx.x * 32 + w * 16;

    f16x8 ones;
    #pragma unroll
    for (int i = 0; i < 8; i++) ones[i] = (f16)1.0f;

    f32x4 acc[4], accC = (f32x4){0.f, 0.f, 0.f, 0.f};
    #pragma unroll
    for (int ni = 0; ni < 4; ni++) acc[ni] = (f32x4){0.f, 0.f, 0.f, 0.f};
    const float* arow = A + (size_t)(mbase + l15) * KA;
    for (int step = 0; step < 38; step++) {
        int kb = step * 32 + lk * 8;
        f32x4 q0 = *(const f32x4*)(arow + kb);
        f32x4 q1 = *(const f32x4*)(arow + kb + 4);
        f16x8 a;
        a[0] = (f16)q0.x; a[1] = (f16)q0.y; a[2] = (f16)q0.z; a[3] = (f16)q0.w;
        a[4] = (f16)q1.x; a[5] = (f16)q1.y; a[6] = (f16)q1.z; a[7] = (f16)q1.w;
        #pragma unroll
        for (int ni = 0; ni < 4; ni++) {
            f16x8 bf = *(const f16x8*)&shembT[(ni * 16 + l15) * KA + kb];
            acc[ni] = __builtin_amdgcn_mfma_f32_16x16x32_f16(a, bf, acc[ni], 0, 0, 0);
        }
        accC = __builtin_amdgcn_mfma_f32_16x16x32_f16(a, ones, accC, 0, 0, 0);
    }
    #pragma unroll
    for (int ni = 0; ni < 4; ni++)
        #pragma unroll
        for (int j = 0; j < 4; j++)
            s_agg[w][(lk * 4 + j) * 72 + ni * 16 + l15] = (f16)acc[ni][j];

    f16x8 a2[2];
    a2[0] = *(const f16x8*)&s_agg[w][l15 * 72 + lk * 8];
    a2[1] = *(const f16x8*)&s_agg[w][l15 * 72 + 32 + lk * 8];
    f32x4 p[4];
    #pragma unroll
    for (int ni = 0; ni < 4; ni++) p[ni] = (f32x4){0.f, 0.f, 0.f, 0.f};
    #pragma unroll
    for (int ks = 0; ks < 2; ks++)
        #pragma unroll
        for (int ni = 0; ni < 4; ni++) {
            f16x8 bf = *(const f16x8*)&s_w1[(ni * 16 + l15) * 72 + ks * 32 + lk * 8];
            p[ni] = __builtin_amdgcn_mfma_f32_16x16x32_f16(a2[ks], bf, p[ni], 0, 0, 0);
        }
    #pragma unroll
    for (int ni = 0; ni < 4; ni++) {
        int n = ni * 16 + l15;
        float bn = b1[n];
        #pragma unroll
        for (int j = 0; j < 4; j++) {
            float cnt = accC[j];
            float h = tanhf(fmaf(cnt, bn, p[ni][j]) / fmaxf(cnt, 1.f));
            h1T[n * KA + mbase + lk * 4 + j] = (f16)h;
        }
    }
}

// ---------------- gcn2: [R14-verified math] 38 blocks x 128 thr ----------------
__global__ __launch_bounds__(128) void gcn2_mfma(const float* __restrict__ A,
                                                 const f16* __restrict__ h1T,
                                                 const float* __restrict__ W2,
                                                 const float* __restrict__ b2,
                                                 const float* __restrict__ Wp1,
                                                 const float* __restrict__ bp1,
                                                 const float* __restrict__ Wp2,
                                                 const float* __restrict__ bp2,
                                                 const float* __restrict__ Wm,
                                                 f16* __restrict__ eh16,
                                                 f16* __restrict__ esWT) {
    __shared__ __align__(16) f16 s_w2[DD * 72], s_p1[DD * 72], s_p2[DD * 72], s_wm[DD * 72];
    __shared__ __align__(16) f16 s_buf[2][16 * 72];
    __shared__ __align__(16) float s_o2[2][16 * 68];
    int tid = threadIdx.x;
    for (int i = tid; i < DD * DD; i += 128) {
        int n = i >> 6, k = i & 63;
        s_w2[n * 72 + k] = (f16)W2[i];
        s_p1[n * 72 + k] = (f16)Wp1[i];
        s_p2[n * 72 + k] = (f16)Wp2[i];
        s_wm[n * 72 + k] = (f16)Wm[i];
    }
    __syncthreads();

    int lane = tid & 63, w = tid >> 6;
    int l15 = lane & 15, lk = lane >> 4;
    int mbase = blockIdx.x * 32 + w * 16;

    f16x8 ones;
    #pragma unroll
    for (int i = 0; i < 8; i++) ones[i] = (f16)1.0f;

    f32x4 acc[4], accC = (f32x4){0.f, 0.f, 0.f, 0.f};
    #pragma unroll
    for (int ni = 0; ni < 4; ni++) acc[ni] = (f32x4){0.f, 0.f, 0.f, 0.f};
    const float* arow = A + (size_t)(mbase + l15) * KA;
    for (int step = 0; step < 38; step++) {
        int kb = step * 32 + lk * 8;
        f32x4 q0 = *(const f32x4*)(arow + kb);
        f32x4 q1 = *(const f32x4*)(arow + kb + 4);
        f16x8 a;
        a[0] = (f16)q0.x; a[1] = (f16)q0.y; a[2] = (f16)q0.z; a[3] = (f16)q0.w;
        a[4] = (f16)q1.x; a[5] = (f16)q1.y; a[6] = (f16)q1.z; a[7] = (f16)q1.w;
        #pragma unroll
        for (int ni = 0; ni < 4; ni++) {
            f16x8 bf = *(const f16x8*)&h1T[(ni * 16 + l15) * KA + kb];
            acc[ni] = __builtin_amdgcn_mfma_f32_16x16x32_f16(a, bf, acc[ni], 0, 0, 0);
        }
        accC = __builtin_amdgcn_mfma_f32_16x16x32_f16(a, ones, accC, 0, 0, 0);
    }
    #pragma unroll
    for (int ni = 0; ni < 4; ni++)
        #pragma unroll
        for (int j = 0; j < 4; j++)
            s_buf[w][(lk * 4 + j) * 72 + ni * 16 + l15] = (f16)acc[ni][j];

    #define GEMM64(SWT, POUT)                                                        \
    {                                                                                \
        f16x8 a2[2];                                                                 \
        a2[0] = *(const f16x8*)&s_buf[w][l15 * 72 + lk * 8];                         \
        a2[1] = *(const f16x8*)&s_buf[w][l15 * 72 + 32 + lk * 8];                    \
        _Pragma("unroll")                                                            \
        for (int ni = 0; ni < 4; ni++) POUT[ni] = (f32x4){0.f, 0.f, 0.f, 0.f};       \
        _Pragma("unroll")                                                            \
        for (int ks = 0; ks < 2; ks++)                                               \
            _Pragma("unroll")                                                        \
            for (int ni = 0; ni < 4; ni++) {                                         \
                f16x8 bf = *(const f16x8*)&SWT[(ni * 16 + l15) * 72 + ks * 32 + lk * 8]; \
                POUT[ni] = __builtin_amdgcn_mfma_f32_16x16x32_f16(a2[ks], bf, POUT[ni], 0, 0, 0); \
            }                                                                        \
    }

    f32x4 p[4];
    GEMM64(s_w2, p);
    #pragma unroll
    for (int ni = 0; ni < 4; ni++) {
        int n = ni * 16 + l15;
        float bn = b2[n];
        #pragma unroll
        for (int j = 0; j < 4; j++) {
            float cnt = accC[j];
            float h = tanhf(fmaf(cnt, bn, p[ni][j]) / fmaxf(cnt, 1.f));
            s_buf[w][(lk * 4 + j) * 72 + n] = (f16)h;
        }
    }
    GEMM64(s_p1, p);
    #pragma unroll
    for (int ni = 0; ni < 4; ni++) {
        int n = ni * 16 + l15;
        float bn = bp1[n];
        #pragma unroll
        for (int j = 0; j < 4; j++) {
            float t = p[ni][j] + bn;
            t = t > 0.f ? t : expm1f(t);
            s_buf[w][(lk * 4 + j) * 72 + n] = (f16)t;
        }
    }
    GEMM64(s_p2, p);
    #pragma unroll
    for (int ni = 0; ni < 4; ni++) {
        int n = ni * 16 + l15;
        float bn = bp2[n];
        #pragma unroll
        for (int j = 0; j < 4; j++)
            s_o2[w][(lk * 4 + j) * 68 + n] = p[ni][j] + bn;
    }
    for (int r = 0; r < 16; r++) {
        float v = s_o2[w][r * 68 + lane];
        float sq = v * v;
        #pragma unroll
        for (int off = 1; off < 64; off <<= 1) sq += __shfl_xor(sq, off);
        float rr = v / sqrtf(sq);
        int node = mbase + r;
        if (node < NU) eh16[node * DD + lane] = (f16)rr;
        s_buf[w][r * 72 + lane] = (f16)rr;
    }
    GEMM64(s_wm, p);
    #pragma unroll
    for (int ni = 0; ni < 4; ni++) {
        int n = ni * 16 + l15;
        #pragma unroll
        for (int j = 0; j < 4; j++) {
            int node = mbase + lk * 4 + j;
            if (node >= NU && node < NSH)
                esWT[n * KPAD + (node - NU)] = (f16)p[ni][j];
        }
    }
    #undef GEMM64
}

// ---------------- synd_v4: SPAD LDS, NT loads, 12 steps + masked tail ----------------
__global__ __launch_bounds__(256) void synd_v4(const float* __restrict__ P,
                                               const f16* __restrict__ esWT,
                                               const float* __restrict__ bm,
                                               float* __restrict__ e_pre,
                                               float* __restrict__ stats) {
    __shared__ __align__(16) f16 s_P[64 * SPAD];
    __shared__ float s_stats[128];
    int tid = threadIdx.x;
    if (tid < 128) s_stats[tid] = 0.f;

    if (tid < 64)
        *(uint32_t*)&s_P[tid * SPAD + 390] = 0u;

    const float* Pb = P + (size_t)blockIdx.x * 64 * NI;
    for (int it = 0; it < 25; it++) {
        int f = it * 1024 + tid * 4;
        if (f < 64 * NI) {
            f32x4 v = __builtin_nontemporal_load((const f32x4*)(Pb + f));
            int row = f / NI;
            int col = f - row * NI;
            *(f16x2*)&s_P[row * SPAD + col] = (f16x2){(f16)v.x, (f16)v.y};
            int row2 = row, col2 = col + 2;
            if (col2 == NI) { row2 = row + 1; col2 = 0; }
            *(f16x2*)&s_P[row2 * SPAD + col2] = (f16x2){(f16)v.z, (f16)v.w};
        }
    }
    __syncthreads();

    int lane = tid & 63, w = tid >> 6;
    int l15 = lane & 15, lk = lane >> 4;
    int rowbase = blockIdx.x * 64 + w * 16;

    f32x4 acc[5];
    #pragma unroll
    for (int ni = 0; ni < 5; ni++) acc[ni] = (f32x4){0.f, 0.f, 0.f, 0.f};

    f16x8 ones;
    #pragma unroll
    for (int i = 0; i < 8; i++) ones[i] = (f16)1.0f;

    const f16* arow = &s_P[(w * 16 + l15) * SPAD];
    const f16* bp[4];
    #pragma unroll
    for (int ni = 0; ni < 4; ni++)
        bp[ni] = esWT + (size_t)(ni * 16 + l15) * KPAD;

    for (int step = 0; step < 12; step++) {
        int kb = step * 32 + lk * 8;
        f16x8 a = *(const f16x8*)(arow + kb);
        f16x8 bfr[4];
        #pragma unroll
        for (int ni = 0; ni < 4; ni++)
            bfr[ni] = *(const f16x8*)(bp[ni] + kb);
        #pragma unroll
        for (int ni = 0; ni < 4; ni++)
            acc[ni] = __builtin_amdgcn_mfma_f32_16x16x32_f16(a, bfr[ni], acc[ni], 0, 0, 0);
        acc[4] = __builtin_amdgcn_mfma_f32_16x16x32_f16(a, ones, acc[4], 0, 0, 0);
    }
    {
        f16x8 az = (f16x8)(f16)0.f;
        f16x8 av = *(const f16x8*)(arow + 384);
        f16x8 a = (lk == 0) ? av : az;
        f16x8 bfr[4];
        #pragma unroll
        for (int ni = 0; ni < 4; ni++)
            bfr[ni] = *(const f16x8*)(bp[ni] + 384 + lk * 8);
        #pragma unroll
        for (int ni = 0; ni < 4; ni++)
            acc[ni] = __builtin_amdgcn_mfma_f32_16x16x32_f16(a, bfr[ni], acc[ni], 0, 0, 0);
        acc[4] = __builtin_amdgcn_mfma_f32_16x16x32_f16(a, ones, acc[4], 0, 0, 0);
    }

    float bmv[4];
    #pragma unroll
    for (int ni = 0; ni < 4; ni++) bmv[ni] = bm[ni * 16 + l15];

    #pragma unroll
    for (int ni = 0; ni < 4; ni++) {
        float s = 0.f, q = 0.f;
        #pragma unroll
        for (int j = 0; j < 4; j++) {
            float v = acc[ni][j] / acc[4][j] + bmv[ni];
            int row = rowbase + lk * 4 + j;
            e_pre[(size_t)row * DD + ni * 16 + l15] = v;
            s += v;
            q = fmaf(v, v, q);
        }
        s += __shfl_xor(s, 16); s += __shfl_xor(s, 32);
        q += __shfl_xor(q, 16); q += __shfl_xor(q, 32);
        if (lk == 0) {
            atomicAdd(&s_stats[ni * 16 + l15], s);
            atomicAdd(&s_stats[64 + ni * 16 + l15], q);
        }
    }
    __syncthreads();
    if (tid < 128) atomicAdd(&stats[tid], s_stats[tid]);
}

// ---------------- out: 4 col-groups (plain stores) ----------------
__global__ __launch_bounds__(256) void out_fused(const float* __restrict__ e_pre,
                                                 const f16* __restrict__ eh16,
                                                 const float* __restrict__ stats,
                                                 const float* __restrict__ gamma,
                                                 const float* __restrict__ beta,
                                                 float* __restrict__ out) {
    __shared__ __align__(16) f16 s_eh[256 * DD];
    __shared__ float s_bn[128];
    int tid = threadIdx.x;
    int cg = blockIdx.x;
    int t0 = (cg == 0) ? 0 : cg * 3 + 1;
    int nt = (cg == 0) ? 4 : 3;
    int cbase = t0 * 64;
    int nrows = nt * 64;

    if (tid < 64) {
        float mu  = stats[tid] * (1.0f / 65536.0f);
        float ex2 = stats[64 + tid] * (1.0f / 65536.0f);
        float var = ex2 - mu * mu;
        float rstd = 1.0f / sqrtf(var + 1e-5f);
        float sc = rstd * gamma[tid];
        s_bn[tid] = sc;
        s_bn[64 + tid] = beta[tid] - mu * sc;
    }

    const uint4* src = (const uint4*)(eh16 + (size_t)cbase * DD);
    int nchunks = nrows * 8;
    for (int c = tid; c < nchunks; c += 256) {
        int row = c >> 3, slot = c & 7;
        uint4 v = src[c];
        *(uint4*)&s_eh[row * DD + ((slot ^ (row & 7)) << 3)] = v;
    }
    __syncthreads();

    int lane = tid & 63, w = tid >> 6;
    int l15 = lane & 15, lk = lane >> 4;
    int r0 = blockIdx.y * 64 + w * 16;

    f16x8 afr[2];
    {
        const float* pr = e_pre + (size_t)(r0 + l15) * DD;
        #pragma unroll
        for (int ks = 0; ks < 2; ks++) {
            int kb = ks * 32 + lk * 8;
            f32x4 v0 = *(const f32x4*)&pr[kb];
            f32x4 v1 = *(const f32x4*)&pr[kb + 4];
            f16x8 a;
            #pragma unroll
            for (int i = 0; i < 4; i++) {
                a[i]     = (f16)fmaxf(fmaf(v0[i], s_bn[kb + i],     s_bn[64 + kb + i]),     0.f);
                a[4 + i] = (f16)fmaxf(fmaf(v1[i], s_bn[kb + 4 + i], s_bn[64 + kb + 4 + i]), 0.f);
            }
            afr[ks] = a;
        }
    }

    for (int tt = 0; tt < nt; tt++) {
        f32x4 acc[4];
        #pragma unroll
        for (int c16 = 0; c16 < 4; c16++) acc[c16] = (f32x4){0.f, 0.f, 0.f, 0.f};
        #pragma unroll
        for (int c16 = 0; c16 < 4; c16++) {
            int lc = tt * 64 + c16 * 16 + l15;
            #pragma unroll
            for (int ks = 0; ks < 2; ks++) {
                int slot = (ks * 4 + lk) ^ (lc & 7);
                f16x8 b = *(const f16x8*)&s_eh[lc * DD + (slot << 3)];
                acc[c16] = __builtin_amdgcn_mfma_f32_16x16x32_f16(afr[ks], b, acc[c16], 0, 0, 0);
            }
        }
        #pragma unroll
        for (int c16 = 0; c16 < 4; c16++) {
            int col = cbase + tt * 64 + c16 * 16 + l15;
            if (col < NU) {
                #pragma unroll
                for (int j = 0; j < 4; j++) {
                    int row = r0 + lk * 4 + j;
                    out[(size_t)row * NU + col] = acc[c16][j];
                }
            }
        }
    }
}

// ---------------- launcher: front duplicated for timing split ----------------
extern "C" void kernel_launch(void* const* d_in, const int* in_sizes, int n_in,
                              void* d_out, int out_size, void* d_ws, size_t ws_size,
                              hipStream_t stream) {
    const int*   eSH   = (const int*)d_in[0];
    const float* presc = (const float*)d_in[3];
    const float* shemb = (const float*)d_in[4];
    const float* W1  = (const float*)d_in[5];
    const float* b1  = (const float*)d_in[6];
    const float* W2  = (const float*)d_in[7];
    const float* b2  = (const float*)d_in[8];
    const float* Wp1 = (const float*)d_in[9];
    const float* bp1 = (const float*)d_in[10];
    const float* Wp2 = (const float*)d_in[11];
    const float* bp2 = (const float*)d_in[12];
    const float* Wm  = (const float*)d_in[13];
    const float* bm  = (const float*)d_in[14];
    const float* gam = (const float*)d_in[15];
    const float* bet = (const float*)d_in[16];

    float* ws     = (float*)d_ws;
    float* stats  = ws + OFF_STATS;
    f16*   esWT   = (f16*)(ws + OFF_ESWT);
    f16*   eh16   = (f16*)(ws + OFF_EH);
    f16*   shembT = (f16*)(ws + OFF_SHEMBT);
    f16*   h1T    = (f16*)(ws + OFF_H1T);
    float* e_pre  = ws + OFF_EPRE;
    float* A      = ws + OFF_EPRE;   // aliased: A dead before synd writes e_pre
    float* out    = (float*)d_out;

    // ---- front pass 1 ----
    prep_kernel<<<1749, 256, 0, stream>>>(shemb, A, shembT, stats, esWT, eh16);
    build_A<<<391, 256, 0, stream>>>(eSH, A);
    gcn1_mfma<<<38, 128, 0, stream>>>(A, shembT, W1, b1, h1T);
    gcn2_mfma<<<38, 128, 0, stream>>>(A, h1T, W2, b2, Wp1, bp1, Wp2, bp2, Wm, eh16, esWT);
    // ---- front pass 2 (measurement duplicate; prep re-zeros A so build_A is exact;
    //      all outputs rebuilt bit-identically) ----
    prep_kernel<<<1749, 256, 0, stream>>>(shemb, A, shembT, stats, esWT, eh16);
    build_A<<<391, 256, 0, stream>>>(eSH, A);
    gcn1_mfma<<<38, 128, 0, stream>>>(A, shembT, W1, b1, h1T);
    gcn2_mfma<<<38, 128, 0, stream>>>(A, h1T, W2, b2, Wp1, bp1, Wp2, bp2, Wm, eh16, esWT);

    synd_v4<<<1024, 256, 0, stream>>>(presc, esWT, bm, e_pre, stats);
    out_fused<<<dim3(4, 1024), 256, 0, stream>>>(e_pre, eh16, stats, gam, bet, out);
}

// Round 22
// 216.243 us; speedup vs baseline: 1.3392x; 1.3392x over previous
//
#include <hip/hip_runtime.h>
#include <math.h>

#define NSH 1195
#define NU  805
#define NI  390
#define DD  64
#define BROWS 65536
#define ESH 100000
#define KPAD 416    // esWT row stride (global)
#define NUPAD 832
#define KA  1216    // dense-A row stride & padded node count (38*32)

typedef _Float16 f16;
typedef _Float16 f16x2 __attribute__((ext_vector_type(2)));
typedef _Float16 f16x8 __attribute__((ext_vector_type(8)));
typedef float f32x2 __attribute__((ext_vector_type(2)));
typedef float f32x4 __attribute__((ext_vector_type(4)));

// ---------------- ws layout (float units) ----------------
#define OFF_STATS  0u         // 128
#define OFF_ESWT   128u       // 64*416 f16
#define OFF_EH     13440u     // 832*64 f16
#define OFF_SHEMBT 40064u     // 64*1216 f16
#define OFF_H1T    78976u     // 64*1216 f16
#define OFF_EPRE   117888u    // e_pre 4194304 f32; A (1216*1216 f32) aliases its head

// ---------------- prep: zero A + build shembT + zero stats/esWT-pad/eh16-pad ----------------
__global__ __launch_bounds__(256) void prep_kernel(const float* __restrict__ shemb,
                                                   float* __restrict__ A,
                                                   f16* __restrict__ shembT,
                                                   float* __restrict__ stats,
                                                   f16* __restrict__ esWT,
                                                   f16* __restrict__ eh16) {
    int b = blockIdx.x, tid = threadIdx.x;
    if (b < 1444) {
        int i = b * 256 + tid;
        *(f32x4*)&A[i * 4] = (f32x4){0.f, 0.f, 0.f, 0.f};
    } else if (b < 1748) {
        int i = (b - 1444) * 256 + tid;
        int d = i / KA, k = i - d * KA;
        shembT[i] = (k < NSH) ? (f16)shemb[k * DD + d] : (f16)0.f;
    } else {
        for (int i = tid; i < 128; i += 256) stats[i] = 0.f;
        for (int i = tid; i < 832; i += 256) {
            int d = i / 13, j = i - d * 13;
            *(uint32_t*)&esWT[d * KPAD + 390 + j * 2] = 0u;
        }
        for (int i = tid; i < 864; i += 256)
            ((uint32_t*)eh16)[NU * 32 + i] = 0u;
    }
}

// ---------------- build dense A: A[dst][src] += 1 ----------------
__global__ __launch_bounds__(256) void build_A(const int* __restrict__ edges,
                                               float* __restrict__ A) {
    int e = blockIdx.x * 256 + threadIdx.x;
    if (e < ESH)
        atomicAdd(&A[edges[ESH + e] * KA + edges[e]], 1.0f);
}

// ---------------- gcn1: [R14-verified math] 38 blocks x 128 thr ----------------
__global__ __launch_bounds__(128) void gcn1_mfma(const float* __restrict__ A,
                                                 const f16* __restrict__ shembT,
                                                 const float* __restrict__ W1,
                                                 const float* __restrict__ b1,
                                                 f16* __restrict__ h1T) {
    __shared__ __align__(16) f16 s_w1[DD * 72];
    __shared__ __align__(16) f16 s_agg[2][16 * 72];
    int tid = threadIdx.x;
    for (int i = tid; i < DD * DD; i += 128)
        s_w1[(i >> 6) * 72 + (i & 63)] = (f16)W1[i];
    __syncthreads();

    int lane = tid & 63, w = tid >> 6;
    int l15 = lane & 15, lk = lane >> 4;
    int mbase = blockIdx.x * 32 + w * 16;

    f16x8 ones;
    #pragma unroll
    for (int i = 0; i < 8; i++) ones[i] = (f16)1.0f;

    f32x4 acc[4], accC = (f32x4){0.f, 0.f, 0.f, 0.f};
    #pragma unroll
    for (int ni = 0; ni < 4; ni++) acc[ni] = (f32x4){0.f, 0.f, 0.f, 0.f};
    const float* arow = A + (size_t)(mbase + l15) * KA;
    for (int step = 0; step < 38; step++) {
        int kb = step * 32 + lk * 8;
        f32x4 q0 = *(const f32x4*)(arow + kb);
        f32x4 q1 = *(const f32x4*)(arow + kb + 4);
        f16x8 a;
        a[0] = (f16)q0.x; a[1] = (f16)q0.y; a[2] = (f16)q0.z; a[3] = (f16)q0.w;
        a[4] = (f16)q1.x; a[5] = (f16)q1.y; a[6] = (f16)q1.z; a[7] = (f16)q1.w;
        #pragma unroll
        for (int ni = 0; ni < 4; ni++) {
            f16x8 bf = *(const f16x8*)&shembT[(ni * 16 + l15) * KA + kb];
            acc[ni] = __builtin_amdgcn_mfma_f32_16x16x32_f16(a, bf, acc[ni], 0, 0, 0);
        }
        accC = __builtin_amdgcn_mfma_f32_16x16x32_f16(a, ones, accC, 0, 0, 0);
    }
    #pragma unroll
    for (int ni = 0; ni < 4; ni++)
        #pragma unroll
        for (int j = 0; j < 4; j++)
            s_agg[w][(lk * 4 + j) * 72 + ni * 16 + l15] = (f16)acc[ni][j];

    f16x8 a2[2];
    a2[0] = *(const f16x8*)&s_agg[w][l15 * 72 + lk * 8];
    a2[1] = *(const f16x8*)&s_agg[w][l15 * 72 + 32 + lk * 8];
    f32x4 p[4];
    #pragma unroll
    for (int ni = 0; ni < 4; ni++) p[ni] = (f32x4){0.f, 0.f, 0.f, 0.f};
    #pragma unroll
    for (int ks = 0; ks < 2; ks++)
        #pragma unroll
        for (int ni = 0; ni < 4; ni++) {
            f16x8 bf = *(const f16x8*)&s_w1[(ni * 16 + l15) * 72 + ks * 32 + lk * 8];
            p[ni] = __builtin_amdgcn_mfma_f32_16x16x32_f16(a2[ks], bf, p[ni], 0, 0, 0);
        }
    #pragma unroll
    for (int ni = 0; ni < 4; ni++) {
        int n = ni * 16 + l15;
        float bn = b1[n];
        #pragma unroll
        for (int j = 0; j < 4; j++) {
            float cnt = accC[j];
            float h = tanhf(fmaf(cnt, bn, p[ni][j]) / fmaxf(cnt, 1.f));
            h1T[n * KA + mbase + lk * 4 + j] = (f16)h;
        }
    }
}

// ---------------- gcn2: [R14-verified math] 38 blocks x 128 thr ----------------
__global__ __launch_bounds__(128) void gcn2_mfma(const float* __restrict__ A,
                                                 const f16* __restrict__ h1T,
                                                 const float* __restrict__ W2,
                                                 const float* __restrict__ b2,
                                                 const float* __restrict__ Wp1,
                                                 const float* __restrict__ bp1,
                                                 const float* __restrict__ Wp2,
                                                 const float* __restrict__ bp2,
                                                 const float* __restrict__ Wm,
                                                 f16* __restrict__ eh16,
                                                 f16* __restrict__ esWT) {
    __shared__ __align__(16) f16 s_w2[DD * 72], s_p1[DD * 72], s_p2[DD * 72], s_wm[DD * 72];
    __shared__ __align__(16) f16 s_buf[2][16 * 72];
    __shared__ __align__(16) float s_o2[2][16 * 68];
    int tid = threadIdx.x;
    for (int i = tid; i < DD * DD; i += 128) {
        int n = i >> 6, k = i & 63;
        s_w2[n * 72 + k] = (f16)W2[i];
        s_p1[n * 72 + k] = (f16)Wp1[i];
        s_p2[n * 72 + k] = (f16)Wp2[i];
        s_wm[n * 72 + k] = (f16)Wm[i];
    }
    __syncthreads();

    int lane = tid & 63, w = tid >> 6;
    int l15 = lane & 15, lk = lane >> 4;
    int mbase = blockIdx.x * 32 + w * 16;

    f16x8 ones;
    #pragma unroll
    for (int i = 0; i < 8; i++) ones[i] = (f16)1.0f;

    f32x4 acc[4], accC = (f32x4){0.f, 0.f, 0.f, 0.f};
    #pragma unroll
    for (int ni = 0; ni < 4; ni++) acc[ni] = (f32x4){0.f, 0.f, 0.f, 0.f};
    const float* arow = A + (size_t)(mbase + l15) * KA;
    for (int step = 0; step < 38; step++) {
        int kb = step * 32 + lk * 8;
        f32x4 q0 = *(const f32x4*)(arow + kb);
        f32x4 q1 = *(const f32x4*)(arow + kb + 4);
        f16x8 a;
        a[0] = (f16)q0.x; a[1] = (f16)q0.y; a[2] = (f16)q0.z; a[3] = (f16)q0.w;
        a[4] = (f16)q1.x; a[5] = (f16)q1.y; a[6] = (f16)q1.z; a[7] = (f16)q1.w;
        #pragma unroll
        for (int ni = 0; ni < 4; ni++) {
            f16x8 bf = *(const f16x8*)&h1T[(ni * 16 + l15) * KA + kb];
            acc[ni] = __builtin_amdgcn_mfma_f32_16x16x32_f16(a, bf, acc[ni], 0, 0, 0);
        }
        accC = __builtin_amdgcn_mfma_f32_16x16x32_f16(a, ones, accC, 0, 0, 0);
    }
    #pragma unroll
    for (int ni = 0; ni < 4; ni++)
        #pragma unroll
        for (int j = 0; j < 4; j++)
            s_buf[w][(lk * 4 + j) * 72 + ni * 16 + l15] = (f16)acc[ni][j];

    #define GEMM64(SWT, POUT)                                                        \
    {                                                                                \
        f16x8 a2[2];                                                                 \
        a2[0] = *(const f16x8*)&s_buf[w][l15 * 72 + lk * 8];                         \
        a2[1] = *(const f16x8*)&s_buf[w][l15 * 72 + 32 + lk * 8];                    \
        _Pragma("unroll")                                                            \
        for (int ni = 0; ni < 4; ni++) POUT[ni] = (f32x4){0.f, 0.f, 0.f, 0.f};       \
        _Pragma("unroll")                                                            \
        for (int ks = 0; ks < 2; ks++)                                               \
            _Pragma("unroll")                                                        \
            for (int ni = 0; ni < 4; ni++) {                                         \
                f16x8 bf = *(const f16x8*)&SWT[(ni * 16 + l15) * 72 + ks * 32 + lk * 8]; \
                POUT[ni] = __builtin_amdgcn_mfma_f32_16x16x32_f16(a2[ks], bf, POUT[ni], 0, 0, 0); \
            }                                                                        \
    }

    f32x4 p[4];
    GEMM64(s_w2, p);
    #pragma unroll
    for (int ni = 0; ni < 4; ni++) {
        int n = ni * 16 + l15;
        float bn = b2[n];
        #pragma unroll
        for (int j = 0; j < 4; j++) {
            float cnt = accC[j];
            float h = tanhf(fmaf(cnt, bn, p[ni][j]) / fmaxf(cnt, 1.f));
            s_buf[w][(lk * 4 + j) * 72 + n] = (f16)h;
        }
    }
    GEMM64(s_p1, p);
    #pragma unroll
    for (int ni = 0; ni < 4; ni++) {
        int n = ni * 16 + l15;
        float bn = bp1[n];
        #pragma unroll
        for (int j = 0; j < 4; j++) {
            float t = p[ni][j] + bn;
            t = t > 0.f ? t : expm1f(t);
            s_buf[w][(lk * 4 + j) * 72 + n] = (f16)t;
        }
    }
    GEMM64(s_p2, p);
    #pragma unroll
    for (int ni = 0; ni < 4; ni++) {
        int n = ni * 16 + l15;
        float bn = bp2[n];
        #pragma unroll
        for (int j = 0; j < 4; j++)
            s_o2[w][(lk * 4 + j) * 68 + n] = p[ni][j] + bn;
    }
    for (int r = 0; r < 16; r++) {
        float v = s_o2[w][r * 68 + lane];
        float sq = v * v;
        #pragma unroll
        for (int off = 1; off < 64; off <<= 1) sq += __shfl_xor(sq, off);
        float rr = v / sqrtf(sq);
        int node = mbase + r;
        if (node < NU) eh16[node * DD + lane] = (f16)rr;
        s_buf[w][r * 72 + lane] = (f16)rr;
    }
    GEMM64(s_wm, p);
    #pragma unroll
    for (int ni = 0; ni < 4; ni++) {
        int n = ni * 16 + l15;
        #pragma unroll
        for (int j = 0; j < 4; j++) {
            int node = mbase + lk * 4 + j;
            if (node >= NU && node < NSH)
                esWT[n * KPAD + (node - NU)] = (f16)p[ni][j];
        }
    }
    #undef GEMM64
}

// ---------------- synd_v5: NO LDS staging (zero reuse) -- direct NT f32x2 fragment loads,
//                  reg f16 convert, 12 full steps + masked tail; rowsum via ones-MFMA ----------------
__global__ __launch_bounds__(256) void synd_v5(const float* __restrict__ P,
                                               const f16* __restrict__ esWT,
                                               const float* __restrict__ bm,
                                               float* __restrict__ e_pre,
                                               float* __restrict__ stats) {
    __shared__ float s_stats[128];
    int tid = threadIdx.x;
    if (tid < 128) s_stats[tid] = 0.f;
    __syncthreads();

    int lane = tid & 63, w = tid >> 6;
    int l15 = lane & 15, lk = lane >> 4;
    int rowbase = blockIdx.x * 64 + w * 16;
    // row stride 390 f32 = 1560 B (8B-aligned) -> f32x2 loads are always aligned
    const float* prow = P + (size_t)(rowbase + l15) * NI;

    f32x4 acc[5];
    #pragma unroll
    for (int ni = 0; ni < 5; ni++) acc[ni] = (f32x4){0.f, 0.f, 0.f, 0.f};

    f16x8 ones;
    #pragma unroll
    for (int i = 0; i < 8; i++) ones[i] = (f16)1.0f;

    const f16* bp[4];
    #pragma unroll
    for (int ni = 0; ni < 4; ni++)
        bp[ni] = esWT + (size_t)(ni * 16 + l15) * KPAD;

    // 12 full steps: cols 0..383
    for (int step = 0; step < 12; step++) {
        int kb = step * 32 + lk * 8;
        f32x2 q0 = __builtin_nontemporal_load((const f32x2*)(prow + kb));
        f32x2 q1 = __builtin_nontemporal_load((const f32x2*)(prow + kb + 2));
        f32x2 q2 = __builtin_nontemporal_load((const f32x2*)(prow + kb + 4));
        f32x2 q3 = __builtin_nontemporal_load((const f32x2*)(prow + kb + 6));
        f16x8 a;
        a[0] = (f16)q0.x; a[1] = (f16)q0.y; a[2] = (f16)q1.x; a[3] = (f16)q1.y;
        a[4] = (f16)q2.x; a[5] = (f16)q2.y; a[6] = (f16)q3.x; a[7] = (f16)q3.y;
        f16x8 bfr[4];
        #pragma unroll
        for (int ni = 0; ni < 4; ni++)
            bfr[ni] = *(const f16x8*)(bp[ni] + kb);
        #pragma unroll
        for (int ni = 0; ni < 4; ni++)
            acc[ni] = __builtin_amdgcn_mfma_f32_16x16x32_f16(a, bfr[ni], acc[ni], 0, 0, 0);
        acc[4] = __builtin_amdgcn_mfma_f32_16x16x32_f16(a, ones, acc[4], 0, 0, 0);
    }
    // tail: cols 384..389 (lk==0 lanes), a[6..7]=0; lk>=1 lanes contribute zero.
    // esWT is zero-padded through col 415 so B reads stay in-bounds & correct.
    {
        f16x8 a = (f16x8)(f16)0.f;
        if (lk == 0) {
            f32x2 q0 = __builtin_nontemporal_load((const f32x2*)(prow + 384));
            f32x2 q1 = __builtin_nontemporal_load((const f32x2*)(prow + 386));
            f32x2 q2 = __builtin_nontemporal_load((const f32x2*)(prow + 388));
            a[0] = (f16)q0.x; a[1] = (f16)q0.y; a[2] = (f16)q1.x;
            a[3] = (f16)q1.y; a[4] = (f16)q2.x; a[5] = (f16)q2.y;
        }
        f16x8 bfr[4];
        #pragma unroll
        for (int ni = 0; ni < 4; ni++)
            bfr[ni] = *(const f16x8*)(bp[ni] + 384 + lk * 8);
        #pragma unroll
        for (int ni = 0; ni < 4; ni++)
            acc[ni] = __builtin_amdgcn_mfma_f32_16x16x32_f16(a, bfr[ni], acc[ni], 0, 0, 0);
        acc[4] = __builtin_amdgcn_mfma_f32_16x16x32_f16(a, ones, acc[4], 0, 0, 0);
    }

    float bmv[4];
    #pragma unroll
    for (int ni = 0; ni < 4; ni++) bmv[ni] = bm[ni * 16 + l15];

    #pragma unroll
    for (int ni = 0; ni < 4; ni++) {
        float s = 0.f, q = 0.f;
        #pragma unroll
        for (int j = 0; j < 4; j++) {
            float v = acc[ni][j] / acc[4][j] + bmv[ni];
            int row = rowbase + lk * 4 + j;
            e_pre[(size_t)row * DD + ni * 16 + l15] = v;
            s += v;
            q = fmaf(v, v, q);
        }
        s += __shfl_xor(s, 16); s += __shfl_xor(s, 32);
        q += __shfl_xor(q, 16); q += __shfl_xor(q, 32);
        if (lk == 0) {
            atomicAdd(&s_stats[ni * 16 + l15], s);
            atomicAdd(&s_stats[64 + ni * 16 + l15], q);
        }
    }
    __syncthreads();
    if (tid < 128) atomicAdd(&stats[tid], s_stats[tid]);
}

// ---------------- out: 4 col-groups (R20-exact, plain stores) ----------------
__global__ __launch_bounds__(256) void out_fused(const float* __restrict__ e_pre,
                                                 const f16* __restrict__ eh16,
                                                 const float* __restrict__ stats,
                                                 const float* __restrict__ gamma,
                                                 const float* __restrict__ beta,
                                                 float* __restrict__ out) {
    __shared__ __align__(16) f16 s_eh[256 * DD];
    __shared__ float s_bn[128];
    int tid = threadIdx.x;
    int cg = blockIdx.x;
    int t0 = (cg == 0) ? 0 : cg * 3 + 1;
    int nt = (cg == 0) ? 4 : 3;
    int cbase = t0 * 64;
    int nrows = nt * 64;

    if (tid < 64) {
        float mu  = stats[tid] * (1.0f / 65536.0f);
        float ex2 = stats[64 + tid] * (1.0f / 65536.0f);
        float var = ex2 - mu * mu;
        float rstd = 1.0f / sqrtf(var + 1e-5f);
        float sc = rstd * gamma[tid];
        s_bn[tid] = sc;
        s_bn[64 + tid] = beta[tid] - mu * sc;
    }

    const uint4* src = (const uint4*)(eh16 + (size_t)cbase * DD);
    int nchunks = nrows * 8;
    for (int c = tid; c < nchunks; c += 256) {
        int row = c >> 3, slot = c & 7;
        uint4 v = src[c];
        *(uint4*)&s_eh[row * DD + ((slot ^ (row & 7)) << 3)] = v;
    }
    __syncthreads();

    int lane = tid & 63, w = tid >> 6;
    int l15 = lane & 15, lk = lane >> 4;
    int r0 = blockIdx.y * 64 + w * 16;

    f16x8 afr[2];
    {
        const float* pr = e_pre + (size_t)(r0 + l15) * DD;
        #pragma unroll
        for (int ks = 0; ks < 2; ks++) {
            int kb = ks * 32 + lk * 8;
            f32x4 v0 = *(const f32x4*)&pr[kb];
            f32x4 v1 = *(const f32x4*)&pr[kb + 4];
            f16x8 a;
            #pragma unroll
            for (int i = 0; i < 4; i++) {
                a[i]     = (f16)fmaxf(fmaf(v0[i], s_bn[kb + i],     s_bn[64 + kb + i]),     0.f);
                a[4 + i] = (f16)fmaxf(fmaf(v1[i], s_bn[kb + 4 + i], s_bn[64 + kb + 4 + i]), 0.f);
            }
            afr[ks] = a;
        }
    }

    for (int tt = 0; tt < nt; tt++) {
        f32x4 acc[4];
        #pragma unroll
        for (int c16 = 0; c16 < 4; c16++) acc[c16] = (f32x4){0.f, 0.f, 0.f, 0.f};
        #pragma unroll
        for (int c16 = 0; c16 < 4; c16++) {
            int lc = tt * 64 + c16 * 16 + l15;
            #pragma unroll
            for (int ks = 0; ks < 2; ks++) {
                int slot = (ks * 4 + lk) ^ (lc & 7);
                f16x8 b = *(const f16x8*)&s_eh[lc * DD + (slot << 3)];
                acc[c16] = __builtin_amdgcn_mfma_f32_16x16x32_f16(afr[ks], b, acc[c16], 0, 0, 0);
            }
        }
        #pragma unroll
        for (int c16 = 0; c16 < 4; c16++) {
            int col = cbase + tt * 64 + c16 * 16 + l15;
            if (col < NU) {
                #pragma unroll
                for (int j = 0; j < 4; j++) {
                    int row = r0 + lk * 4 + j;
                    out[(size_t)row * NU + col] = acc[c16][j];
                }
            }
        }
    }
}

// ---------------- launcher: 6 nodes ----------------
extern "C" void kernel_launch(void* const* d_in, const int* in_sizes, int n_in,
                              void* d_out, int out_size, void* d_ws, size_t ws_size,
                              hipStream_t stream) {
    const int*   eSH   = (const int*)d_in[0];
    const float* presc = (const float*)d_in[3];
    const float* shemb = (const float*)d_in[4];
    const float* W1  = (const float*)d_in[5];
    const float* b1  = (const float*)d_in[6];
    const float* W2  = (const float*)d_in[7];
    const float* b2  = (const float*)d_in[8];
    const float* Wp1 = (const float*)d_in[9];
    const float* bp1 = (const float*)d_in[10];
    const float* Wp2 = (const float*)d_in[11];
    const float* bp2 = (const float*)d_in[12];
    const float* Wm  = (const float*)d_in[13];
    const float* bm  = (const float*)d_in[14];
    const float* gam = (const float*)d_in[15];
    const float* bet = (const float*)d_in[16];

    float* ws     = (float*)d_ws;
    float* stats  = ws + OFF_STATS;
    f16*   esWT   = (f16*)(ws + OFF_ESWT);
    f16*   eh16   = (f16*)(ws + OFF_EH);
    f16*   shembT = (f16*)(ws + OFF_SHEMBT);
    f16*   h1T    = (f16*)(ws + OFF_H1T);
    float* e_pre  = ws + OFF_EPRE;
    float* A      = ws + OFF_EPRE;   // aliased: A dead before synd writes e_pre
    float* out    = (float*)d_out;

    prep_kernel<<<1749, 256, 0, stream>>>(shemb, A, shembT, stats, esWT, eh16);
    build_A<<<391, 256, 0, stream>>>(eSH, A);
    gcn1_mfma<<<38, 128, 0, stream>>>(A, shembT, W1, b1, h1T);
    gcn2_mfma<<<38, 128, 0, stream>>>(A, h1T, W2, b2, Wp1, bp1, Wp2, bp2, Wm, eh16, esWT);
    synd_v5<<<1024, 256, 0, stream>>>(presc, esWT, bm, e_pre, stats);
    out_fused<<<dim3(4, 1024), 256, 0, stream>>>(e_pre, eh16, stats, gam, bet, out);
}

// Round 23
// 199.223 us; speedup vs baseline: 1.4536x; 1.0854x over previous
//
#include <hip/hip_runtime.h>
#include <math.h>

#define NSH 1195
#define NU  805
#define NI  390
#define DD  64
#define BROWS 65536
#define ESH 100000
#define KPAD 416    // esWT row stride (global)
#define SPAD 392    // s_P row stride: 49*16B -> aligned b128, 2-way banks, 3 blocks/CU
#define NUPAD 832
#define KA  1216    // dense-A row stride & padded node count (38*32)

typedef _Float16 f16;
typedef _Float16 f16x2 __attribute__((ext_vector_type(2)));
typedef _Float16 f16x8 __attribute__((ext_vector_type(8)));
typedef float f32x4 __attribute__((ext_vector_type(4)));

// ---------------- ws layout (float units) ----------------
#define OFF_STATS  0u         // 128
#define OFF_ESWT   128u       // 64*416 f16
#define OFF_EH     13440u     // 832*64 f16
#define OFF_SHEMBT 40064u     // 64*1216 f16
#define OFF_H1T    78976u     // 64*1216 f16
#define OFF_EPRE   117888u    // e_pre 4194304 f32; A (1216*1216 f32) aliases its head

// ---------------- prep: zero A + build shembT + zero stats/esWT-pad/eh16-pad ----------------
__global__ __launch_bounds__(256) void prep_kernel(const float* __restrict__ shemb,
                                                   float* __restrict__ A,
                                                   f16* __restrict__ shembT,
                                                   float* __restrict__ stats,
                                                   f16* __restrict__ esWT,
                                                   f16* __restrict__ eh16) {
    int b = blockIdx.x, tid = threadIdx.x;
    if (b < 1444) {
        int i = b * 256 + tid;
        *(f32x4*)&A[i * 4] = (f32x4){0.f, 0.f, 0.f, 0.f};
    } else if (b < 1748) {
        int i = (b - 1444) * 256 + tid;
        int d = i / KA, k = i - d * KA;
        shembT[i] = (k < NSH) ? (f16)shemb[k * DD + d] : (f16)0.f;
    } else {
        for (int i = tid; i < 128; i += 256) stats[i] = 0.f;
        for (int i = tid; i < 832; i += 256) {
            int d = i / 13, j = i - d * 13;
            *(uint32_t*)&esWT[d * KPAD + 390 + j * 2] = 0u;
        }
        for (int i = tid; i < 864; i += 256)
            ((uint32_t*)eh16)[NU * 32 + i] = 0u;
    }
}

// ---------------- build dense A: A[dst][src] += 1 ----------------
__global__ __launch_bounds__(256) void build_A(const int* __restrict__ edges,
                                               float* __restrict__ A) {
    int e = blockIdx.x * 256 + threadIdx.x;
    if (e < ESH)
        atomicAdd(&A[edges[ESH + e] * KA + edges[e]], 1.0f);
}

// ---------------- gcn1: 38 blocks x 128 thr (2 waves, 32 rows/block) ----------------
__global__ __launch_bounds__(128) void gcn1_mfma(const float* __restrict__ A,
                                                 const f16* __restrict__ shembT,
                                                 const float* __restrict__ W1,
                                                 const float* __restrict__ b1,
                                                 f16* __restrict__ h1T) {
    __shared__ __align__(16) f16 s_w1[DD * 72];
    __shared__ __align__(16) f16 s_agg[2][16 * 72];
    int tid = threadIdx.x;
    for (int i = tid; i < DD * DD; i += 128)
        s_w1[(i >> 6) * 72 + (i & 63)] = (f16)W1[i];
    __syncthreads();

    int lane = tid & 63, w = tid >> 6;
    int l15 = lane & 15, lk = lane >> 4;
    int mbase = blockIdx.x * 32 + w * 16;

    f16x8 ones;
    #pragma unroll
    for (int i = 0; i < 8; i++) ones[i] = (f16)1.0f;

    f32x4 acc[4], accC = (f32x4){0.f, 0.f, 0.f, 0.f};
    #pragma unroll
    for (int ni = 0; ni < 4; ni++) acc[ni] = (f32x4){0.f, 0.f, 0.f, 0.f};
    const float* arow = A + (size_t)(mbase + l15) * KA;
    for (int step = 0; step < 38; step++) {
        int kb = step * 32 + lk * 8;
        f32x4 q0 = *(const f32x4*)(arow + kb);
        f32x4 q1 = *(const f32x4*)(arow + kb + 4);
        f16x8 a;
        a[0] = (f16)q0.x; a[1] = (f16)q0.y; a[2] = (f16)q0.z; a[3] = (f16)q0.w;
        a[4] = (f16)q1.x; a[5] = (f16)q1.y; a[6] = (f16)q1.z; a[7] = (f16)q1.w;
        #pragma unroll
        for (int ni = 0; ni < 4; ni++) {
            f16x8 bf = *(const f16x8*)&shembT[(ni * 16 + l15) * KA + kb];
            acc[ni] = __builtin_amdgcn_mfma_f32_16x16x32_f16(a, bf, acc[ni], 0, 0, 0);
        }
        accC = __builtin_amdgcn_mfma_f32_16x16x32_f16(a, ones, accC, 0, 0, 0);
    }
    #pragma unroll
    for (int ni = 0; ni < 4; ni++)
        #pragma unroll
        for (int j = 0; j < 4; j++)
            s_agg[w][(lk * 4 + j) * 72 + ni * 16 + l15] = (f16)acc[ni][j];

    f16x8 a2[2];
    a2[0] = *(const f16x8*)&s_agg[w][l15 * 72 + lk * 8];
    a2[1] = *(const f16x8*)&s_agg[w][l15 * 72 + 32 + lk * 8];
    f32x4 p[4];
    #pragma unroll
    for (int ni = 0; ni < 4; ni++) p[ni] = (f32x4){0.f, 0.f, 0.f, 0.f};
    #pragma unroll
    for (int ks = 0; ks < 2; ks++)
        #pragma unroll
        for (int ni = 0; ni < 4; ni++) {
            f16x8 bf = *(const f16x8*)&s_w1[(ni * 16 + l15) * 72 + ks * 32 + lk * 8];
            p[ni] = __builtin_amdgcn_mfma_f32_16x16x32_f16(a2[ks], bf, p[ni], 0, 0, 0);
        }
    #pragma unroll
    for (int ni = 0; ni < 4; ni++) {
        int n = ni * 16 + l15;
        float bn = b1[n];
        #pragma unroll
        for (int j = 0; j < 4; j++) {
            float cnt = accC[j];
            float h = tanhf(fmaf(cnt, bn, p[ni][j]) / fmaxf(cnt, 1.f));
            h1T[n * KA + mbase + lk * 4 + j] = (f16)h;
        }
    }
}

// ---------------- gcn2: 38 blocks x 128 thr ----------------
__global__ __launch_bounds__(128) void gcn2_mfma(const float* __restrict__ A,
                                                 const f16* __restrict__ h1T,
                                                 const float* __restrict__ W2,
                                                 const float* __restrict__ b2,
                                                 const float* __restrict__ Wp1,
                                                 const float* __restrict__ bp1,
                                                 const float* __restrict__ Wp2,
                                                 const float* __restrict__ bp2,
                                                 const float* __restrict__ Wm,
                                                 f16* __restrict__ eh16,
                                                 f16* __restrict__ esWT) {
    __shared__ __align__(16) f16 s_w2[DD * 72], s_p1[DD * 72], s_p2[DD * 72], s_wm[DD * 72];
    __shared__ __align__(16) f16 s_buf[2][16 * 72];
    __shared__ __align__(16) float s_o2[2][16 * 68];
    int tid = threadIdx.x;
    for (int i = tid; i < DD * DD; i += 128) {
        int n = i >> 6, k = i & 63;
        s_w2[n * 72 + k] = (f16)W2[i];
        s_p1[n * 72 + k] = (f16)Wp1[i];
        s_p2[n * 72 + k] = (f16)Wp2[i];
        s_wm[n * 72 + k] = (f16)Wm[i];
    }
    __syncthreads();

    int lane = tid & 63, w = tid >> 6;
    int l15 = lane & 15, lk = lane >> 4;
    int mbase = blockIdx.x * 32 + w * 16;

    f16x8 ones;
    #pragma unroll
    for (int i = 0; i < 8; i++) ones[i] = (f16)1.0f;

    f32x4 acc[4], accC = (f32x4){0.f, 0.f, 0.f, 0.f};
    #pragma unroll
    for (int ni = 0; ni < 4; ni++) acc[ni] = (f32x4){0.f, 0.f, 0.f, 0.f};
    const float* arow = A + (size_t)(mbase + l15) * KA;
    for (int step = 0; step < 38; step++) {
        int kb = step * 32 + lk * 8;
        f32x4 q0 = *(const f32x4*)(arow + kb);
        f32x4 q1 = *(const f32x4*)(arow + kb + 4);
        f16x8 a;
        a[0] = (f16)q0.x; a[1] = (f16)q0.y; a[2] = (f16)q0.z; a[3] = (f16)q0.w;
        a[4] = (f16)q1.x; a[5] = (f16)q1.y; a[6] = (f16)q1.z; a[7] = (f16)q1.w;
        #pragma unroll
        for (int ni = 0; ni < 4; ni++) {
            f16x8 bf = *(const f16x8*)&h1T[(ni * 16 + l15) * KA + kb];
            acc[ni] = __builtin_amdgcn_mfma_f32_16x16x32_f16(a, bf, acc[ni], 0, 0, 0);
        }
        accC = __builtin_amdgcn_mfma_f32_16x16x32_f16(a, ones, accC, 0, 0, 0);
    }
    #pragma unroll
    for (int ni = 0; ni < 4; ni++)
        #pragma unroll
        for (int j = 0; j < 4; j++)
            s_buf[w][(lk * 4 + j) * 72 + ni * 16 + l15] = (f16)acc[ni][j];

    #define GEMM64(SWT, POUT)                                                        \
    {                                                                                \
        f16x8 a2[2];                                                                 \
        a2[0] = *(const f16x8*)&s_buf[w][l15 * 72 + lk * 8];                         \
        a2[1] = *(const f16x8*)&s_buf[w][l15 * 72 + 32 + lk * 8];                    \
        _Pragma("unroll")                                                            \
        for (int ni = 0; ni < 4; ni++) POUT[ni] = (f32x4){0.f, 0.f, 0.f, 0.f};       \
        _Pragma("unroll")                                                            \
        for (int ks = 0; ks < 2; ks++)                                               \
            _Pragma("unroll")                                                        \
            for (int ni = 0; ni < 4; ni++) {                                         \
                f16x8 bf = *(const f16x8*)&SWT[(ni * 16 + l15) * 72 + ks * 32 + lk * 8]; \
                POUT[ni] = __builtin_amdgcn_mfma_f32_16x16x32_f16(a2[ks], bf, POUT[ni], 0, 0, 0); \
            }                                                                        \
    }

    f32x4 p[4];
    GEMM64(s_w2, p);
    #pragma unroll
    for (int ni = 0; ni < 4; ni++) {
        int n = ni * 16 + l15;
        float bn = b2[n];
        #pragma unroll
        for (int j = 0; j < 4; j++) {
            float cnt = accC[j];
            float h = tanhf(fmaf(cnt, bn, p[ni][j]) / fmaxf(cnt, 1.f));
            s_buf[w][(lk * 4 + j) * 72 + n] = (f16)h;
        }
    }
    GEMM64(s_p1, p);
    #pragma unroll
    for (int ni = 0; ni < 4; ni++) {
        int n = ni * 16 + l15;
        float bn = bp1[n];
        #pragma unroll
        for (int j = 0; j < 4; j++) {
            float t = p[ni][j] + bn;
            t = t > 0.f ? t : expm1f(t);
            s_buf[w][(lk * 4 + j) * 72 + n] = (f16)t;
        }
    }
    GEMM64(s_p2, p);
    #pragma unroll
    for (int ni = 0; ni < 4; ni++) {
        int n = ni * 16 + l15;
        float bn = bp2[n];
        #pragma unroll
        for (int j = 0; j < 4; j++)
            s_o2[w][(lk * 4 + j) * 68 + n] = p[ni][j] + bn;
    }
    for (int r = 0; r < 16; r++) {
        float v = s_o2[w][r * 68 + lane];
        float sq = v * v;
        #pragma unroll
        for (int off = 1; off < 64; off <<= 1) sq += __shfl_xor(sq, off);
        float rr = v / sqrtf(sq);
        int node = mbase + r;
        if (node < NU) eh16[node * DD + lane] = (f16)rr;
        s_buf[w][r * 72 + lane] = (f16)rr;
    }
    GEMM64(s_wm, p);
    #pragma unroll
    for (int ni = 0; ni < 4; ni++) {
        int n = ni * 16 + l15;
        #pragma unroll
        for (int j = 0; j < 4; j++) {
            int node = mbase + lk * 4 + j;
            if (node >= NU && node < NSH)
                esWT[n * KPAD + (node - NU)] = (f16)p[ni][j];
        }
    }
    #undef GEMM64
}

// ---------------- synd_v4: SPAD=392 LDS (3 blocks/CU), NT loads, 12 steps + masked tail ----------------
__global__ __launch_bounds__(256) void synd_v4(const float* __restrict__ P,
                                               const f16* __restrict__ esWT,
                                               const float* __restrict__ bm,
                                               float* __restrict__ e_pre,
                                               float* __restrict__ stats) {
    __shared__ __align__(16) f16 s_P[64 * SPAD];   // 50176 B
    __shared__ float s_stats[128];
    int tid = threadIdx.x;
    if (tid < 128) s_stats[tid] = 0.f;

    if (tid < 64)
        *(uint32_t*)&s_P[tid * SPAD + 390] = 0u;

    const float* Pb = P + (size_t)blockIdx.x * 64 * NI;
    for (int it = 0; it < 25; it++) {
        int f = it * 1024 + tid * 4;
        if (f < 64 * NI) {
            f32x4 v = __builtin_nontemporal_load((const f32x4*)(Pb + f));
            int row = f / NI;
            int col = f - row * NI;
            *(f16x2*)&s_P[row * SPAD + col] = (f16x2){(f16)v.x, (f16)v.y};
            int row2 = row, col2 = col + 2;
            if (col2 == NI) { row2 = row + 1; col2 = 0; }
            *(f16x2*)&s_P[row2 * SPAD + col2] = (f16x2){(f16)v.z, (f16)v.w};
        }
    }
    __syncthreads();

    int lane = tid & 63, w = tid >> 6;
    int l15 = lane & 15, lk = lane >> 4;
    int rowbase = blockIdx.x * 64 + w * 16;

    f32x4 acc[5];
    #pragma unroll
    for (int ni = 0; ni < 5; ni++) acc[ni] = (f32x4){0.f, 0.f, 0.f, 0.f};

    f16x8 ones;
    #pragma unroll
    for (int i = 0; i < 8; i++) ones[i] = (f16)1.0f;

    const f16* arow = &s_P[(w * 16 + l15) * SPAD];
    const f16* bp[4];
    #pragma unroll
    for (int ni = 0; ni < 4; ni++)
        bp[ni] = esWT + (size_t)(ni * 16 + l15) * KPAD;

    for (int step = 0; step < 12; step++) {
        int kb = step * 32 + lk * 8;
        f16x8 a = *(const f16x8*)(arow + kb);
        f16x8 bfr[4];
        #pragma unroll
        for (int ni = 0; ni < 4; ni++)
            bfr[ni] = *(const f16x8*)(bp[ni] + kb);
        #pragma unroll
        for (int ni = 0; ni < 4; ni++)
            acc[ni] = __builtin_amdgcn_mfma_f32_16x16x32_f16(a, bfr[ni], acc[ni], 0, 0, 0);
        acc[4] = __builtin_amdgcn_mfma_f32_16x16x32_f16(a, ones, acc[4], 0, 0, 0);
    }
    {
        f16x8 az = (f16x8)(f16)0.f;
        f16x8 av = *(const f16x8*)(arow + 384);
        f16x8 a = (lk == 0) ? av : az;
        f16x8 bfr[4];
        #pragma unroll
        for (int ni = 0; ni < 4; ni++)
            bfr[ni] = *(const f16x8*)(bp[ni] + 384 + lk * 8);
        #pragma unroll
        for (int ni = 0; ni < 4; ni++)
            acc[ni] = __builtin_amdgcn_mfma_f32_16x16x32_f16(a, bfr[ni], acc[ni], 0, 0, 0);
        acc[4] = __builtin_amdgcn_mfma_f32_16x16x32_f16(a, ones, acc[4], 0, 0, 0);
    }

    float bmv[4];
    #pragma unroll
    for (int ni = 0; ni < 4; ni++) bmv[ni] = bm[ni * 16 + l15];

    #pragma unroll
    for (int ni = 0; ni < 4; ni++) {
        float s = 0.f, q = 0.f;
        #pragma unroll
        for (int j = 0; j < 4; j++) {
            float v = acc[ni][j] / acc[4][j] + bmv[ni];
            int row = rowbase + lk * 4 + j;
            e_pre[(size_t)row * DD + ni * 16 + l15] = v;
            s += v;
            q = fmaf(v, v, q);
        }
        s += __shfl_xor(s, 16); s += __shfl_xor(s, 32);
        q += __shfl_xor(q, 16); q += __shfl_xor(q, 32);
        if (lk == 0) {
            atomicAdd(&s_stats[ni * 16 + l15], s);
            atomicAdd(&s_stats[64 + ni * 16 + l15], q);
        }
    }
    __syncthreads();
    if (tid < 128) atomicAdd(&stats[tid], s_stats[tid]);
}

// ---------------- out: 4 col-groups (plain stores) ----------------
__global__ __launch_bounds__(256) void out_fused(const float* __restrict__ e_pre,
                                                 const f16* __restrict__ eh16,
                                                 const float* __restrict__ stats,
                                                 const float* __restrict__ gamma,
                                                 const float* __restrict__ beta,
                                                 float* __restrict__ out) {
    __shared__ __align__(16) f16 s_eh[256 * DD];
    __shared__ float s_bn[128];
    int tid = threadIdx.x;
    int cg = blockIdx.x;
    int t0 = (cg == 0) ? 0 : cg * 3 + 1;
    int nt = (cg == 0) ? 4 : 3;
    int cbase = t0 * 64;
    int nrows = nt * 64;

    if (tid < 64) {
        float mu  = stats[tid] * (1.0f / 65536.0f);
        float ex2 = stats[64 + tid] * (1.0f / 65536.0f);
        float var = ex2 - mu * mu;
        float rstd = 1.0f / sqrtf(var + 1e-5f);
        float sc = rstd * gamma[tid];
        s_bn[tid] = sc;
        s_bn[64 + tid] = beta[tid] - mu * sc;
    }

    const uint4* src = (const uint4*)(eh16 + (size_t)cbase * DD);
    int nchunks = nrows * 8;
    for (int c = tid; c < nchunks; c += 256) {
        int row = c >> 3, slot = c & 7;
        uint4 v = src[c];
        *(uint4*)&s_eh[row * DD + ((slot ^ (row & 7)) << 3)] = v;
    }
    __syncthreads();

    int lane = tid & 63, w = tid >> 6;
    int l15 = lane & 15, lk = lane >> 4;
    int r0 = blockIdx.y * 64 + w * 16;

    f16x8 afr[2];
    {
        const float* pr = e_pre + (size_t)(r0 + l15) * DD;
        #pragma unroll
        for (int ks = 0; ks < 2; ks++) {
            int kb = ks * 32 + lk * 8;
            f32x4 v0 = *(const f32x4*)&pr[kb];
            f32x4 v1 = *(const f32x4*)&pr[kb + 4];
            f16x8 a;
            #pragma unroll
            for (int i = 0; i < 4; i++) {
                a[i]     = (f16)fmaxf(fmaf(v0[i], s_bn[kb + i],     s_bn[64 + kb + i]),     0.f);
                a[4 + i] = (f16)fmaxf(fmaf(v1[i], s_bn[kb + 4 + i], s_bn[64 + kb + 4 + i]), 0.f);
            }
            afr[ks] = a;
        }
    }

    for (int tt = 0; tt < nt; tt++) {
        f32x4 acc[4];
        #pragma unroll
        for (int c16 = 0; c16 < 4; c16++) acc[c16] = (f32x4){0.f, 0.f, 0.f, 0.f};
        #pragma unroll
        for (int c16 = 0; c16 < 4; c16++) {
            int lc = tt * 64 + c16 * 16 + l15;
            #pragma unroll
            for (int ks = 0; ks < 2; ks++) {
                int slot = (ks * 4 + lk) ^ (lc & 7);
                f16x8 b = *(const f16x8*)&s_eh[lc * DD + (slot << 3)];
                acc[c16] = __builtin_amdgcn_mfma_f32_16x16x32_f16(afr[ks], b, acc[c16], 0, 0, 0);
            }
        }
        #pragma unroll
        for (int c16 = 0; c16 < 4; c16++) {
            int col = cbase + tt * 64 + c16 * 16 + l15;
            if (col < NU) {
                #pragma unroll
                for (int j = 0; j < 4; j++) {
                    int row = r0 + lk * 4 + j;
                    out[(size_t)row * NU + col] = acc[c16][j];
                }
            }
        }
    }
}

// ---------------- launcher: 6 nodes ----------------
extern "C" void kernel_launch(void* const* d_in, const int* in_sizes, int n_in,
                              void* d_out, int out_size, void* d_ws, size_t ws_size,
                              hipStream_t stream) {
    const int*   eSH   = (const int*)d_in[0];
    const float* presc = (const float*)d_in[3];
    const float* shemb = (const float*)d_in[4];
    const float* W1  = (const float*)d_in[5];
    const float* b1  = (const float*)d_in[6];
    const float* W2  = (const float*)d_in[7];
    const float* b2  = (const float*)d_in[8];
    const float* Wp1 = (const float*)d_in[9];
    const float* bp1 = (const float*)d_in[10];
    const float* Wp2 = (const float*)d_in[11];
    const float* bp2 = (const float*)d_in[12];
    const float* Wm  = (const float*)d_in[13];
    const float* bm  = (const float*)d_in[14];
    const float* gam = (const float*)d_in[15];
    const float* bet = (const float*)d_in[16];

    float* ws     = (float*)d_ws;
    float* stats  = ws + OFF_STATS;
    f16*   esWT   = (f16*)(ws + OFF_ESWT);
    f16*   eh16   = (f16*)(ws + OFF_EH);
    f16*   shembT = (f16*)(ws + OFF_SHEMBT);
    f16*   h1T    = (f16*)(ws + OFF_H1T);
    float* e_pre  = ws + OFF_EPRE;
    float* A      = ws + OFF_EPRE;   // aliased: A dead before synd writes e_pre
    float* out    = (float*)d_out;

    prep_kernel<<<1749, 256, 0, stream>>>(shemb, A, shembT, stats, esWT, eh16);
    build_A<<<391, 256, 0, stream>>>(eSH, A);
    gcn1_mfma<<<38, 128, 0, stream>>>(A, shembT, W1, b1, h1T);
    gcn2_mfma<<<38, 128, 0, stream>>>(A, h1T, W2, b2, Wp1, bp1, Wp2, bp2, Wm, eh16, esWT);
    synd_v4<<<1024, 256, 0, stream>>>(presc, esWT, bm, e_pre, stats);
    out_fused<<<dim3(4, 1024), 256, 0, stream>>>(e_pre, eh16, stats, gam, bet, out);
}